// Round 1
// baseline (404.000 us; speedup 1.0000x reference)
//
#include <hip/hip_runtime.h>
#include <stdint.h>

typedef unsigned short u16;
typedef __attribute__((ext_vector_type(8))) short short8;
typedef __attribute__((ext_vector_type(4))) float f32x4;

#define B_   2
#define NQ_  2048
#define NKV_ 2048
#define D_   2048
#define H_   16
#define HD_  128
#define MM_  (B_*NQ_)   // 4096

// round-to-nearest-even f32 -> bf16
__device__ __forceinline__ u16 f2bf(float f) {
  uint32_t u = __float_as_uint(f);
  u += 0x7fffu + ((u >> 16) & 1u);
  return (u16)(u >> 16);
}

// async global->LDS, 16B per lane; LDS dest is wave-uniform base + lane*16
__device__ __forceinline__ void gload_lds16(const void* g, void* l) {
  __builtin_amdgcn_global_load_lds(
      (const __attribute__((address_space(1))) void*)g,
      (__attribute__((address_space(3))) void*)l, 16, 0, 0);
}

// ---------------------------------------------------------------- casts
__global__ __launch_bounds__(256) void cast_bf16(const float* __restrict__ src,
                                                 u16* __restrict__ dst, int n8) {
  int i = blockIdx.x * 256 + threadIdx.x;
  if (i >= n8) return;
  const float4* s = (const float4*)src + (size_t)i * 2;
  float4 a = s[0], b = s[1];
  short8 o;
  o[0] = (short)f2bf(a.x); o[1] = (short)f2bf(a.y);
  o[2] = (short)f2bf(a.z); o[3] = (short)f2bf(a.w);
  o[4] = (short)f2bf(b.x); o[5] = (short)f2bf(b.y);
  o[6] = (short)f2bf(b.z); o[7] = (short)f2bf(b.w);
  *((short8*)dst + i) = o;
}

__global__ __launch_bounds__(256) void build_bias(const int* __restrict__ labels,
                                                  const unsigned char* __restrict__ mask,
                                                  const float* __restrict__ tb,
                                                  float* __restrict__ out, int n) {
  int i = blockIdx.x * 256 + threadIdx.x;
  if (i < n) out[i] = mask[i] ? -1e30f : tb[labels[i]];
}

// ---------------------------------------------------------------- GEMM C = A @ W^T + bias
// A[M][K], W[N][K] bf16 row-major; 128x128 tile, BK=64, 4 waves (2x2), 16x16x32 MFMA.
// LDS linear for global_load_lds; bank swizzle done by pre-permuting the global
// source chunk (chunk ^= row&7) and applying the same XOR on ds_read addresses.
template<int OUT_BF16>
__global__ __launch_bounds__(256, 2) void gemm_bt(
    const u16* __restrict__ A, const u16* __restrict__ W,
    const float* __restrict__ bias, void* __restrict__ Cout,
    int M, int N, int K)
{
  __shared__ u16 As[128 * 64];
  __shared__ u16 Bs[128 * 64];
  const int tid = threadIdx.x;
  const int w = tid >> 6, l = tid & 63;
  const int lr = l & 15, lg = l >> 4;
  const int nbn = N >> 7;
  const int nwg = gridDim.x;
  int bid = blockIdx.x;
  int swz = (bid & 7) * (nwg >> 3) + (bid >> 3);   // bijective: nwg % 8 == 0
  const int bm = swz / nbn, bn = swz % nbn;
  const int wm = w >> 1, wn = w & 1;

  f32x4 acc[4][4] = {};

  const int sr = w * 32 + (l >> 3);  // staging row (8 rows per glds instr)
  const int sc = l & 7;              // physical 16B chunk within 128B row

  for (int kt = 0; kt < K; kt += 64) {
#pragma unroll
    for (int i = 0; i < 4; ++i) {
      int r = sr + i * 8;
      int gc = kt + ((sc ^ (r & 7)) << 3);  // pre-swizzled source column (elems)
      gload_lds16(A + (size_t)(bm * 128 + r) * K + gc, (char*)As + (w * 32 + i * 8) * 128);
      gload_lds16(W + (size_t)(bn * 128 + r) * K + gc, (char*)Bs + (w * 32 + i * 8) * 128);
    }
    __syncthreads();
#pragma unroll
    for (int ks = 0; ks < 2; ++ks) {
      short8 av[4], bv[4];
#pragma unroll
      for (int mf = 0; mf < 4; ++mf) {
        int row = wm * 64 + mf * 16 + lr;
        int pch = (ks * 4 + lg) ^ (row & 7);
        av[mf] = *(const short8*)((const char*)As + row * 128 + pch * 16);
      }
#pragma unroll
      for (int nf = 0; nf < 4; ++nf) {
        int row = wn * 64 + nf * 16 + lr;
        int pch = (ks * 4 + lg) ^ (row & 7);
        bv[nf] = *(const short8*)((const char*)Bs + row * 128 + pch * 16);
      }
#pragma unroll
      for (int mf = 0; mf < 4; ++mf)
#pragma unroll
        for (int nf = 0; nf < 4; ++nf)
          acc[mf][nf] = __builtin_amdgcn_mfma_f32_16x16x32_bf16(av[mf], bv[nf], acc[mf][nf], 0, 0, 0);
    }
    __syncthreads();
  }

  const int row0 = bm * 128 + wm * 64;
  const int col0 = bn * 128 + wn * 64;
#pragma unroll
  for (int nf = 0; nf < 4; ++nf) {
    int col = col0 + nf * 16 + lr;
    float bb = bias[col];
#pragma unroll
    for (int mf = 0; mf < 4; ++mf) {
#pragma unroll
      for (int r = 0; r < 4; ++r) {
        size_t row = (size_t)(row0 + mf * 16 + lg * 4 + r);
        float vv = acc[mf][nf][r] + bb;
        if (OUT_BF16) ((u16*)Cout)[row * N + col] = f2bf(vv);
        else          ((float*)Cout)[row * N + col] = vv;
      }
    }
  }
}

// ---------------------------------------------------------------- flash attention
// block: 64 q rows (4 waves x 16), kv tiles of 64, HD=128. Online softmax.
// C-layout (verified m89): col = lane&15, row = (lane>>4)*4 + reg.
__global__ __launch_bounds__(256, 2) void attn_fwd(
    const u16* __restrict__ Q, const u16* __restrict__ Kg,
    const u16* __restrict__ Vg, const float* __restrict__ biaskv,
    u16* __restrict__ AO)
{
  __shared__ u16 Ks[64 * 128];     // 16KB, chunk-swizzled via pre-permuted source
  __shared__ u16 Vt[128 * 72];     // 18KB, V transposed [hd][kv], +8 pad
  __shared__ u16 Ps[4][16 * 72];   // per-wave P (16 q x 64 kv, +8 pad)

  const int tid = threadIdx.x;
  const int w = tid >> 6, l = tid & 63;
  const int lr = l & 15, lg = l >> 4;

  int bid = blockIdx.x;
  int swz = (bid & 7) * 128 + (bid >> 3);   // 1024 blocks, XCD-chunked
  const int qt = 31 - (swz & 31);           // heavy blocks first
  const int h  = (swz >> 5) & 15;
  const int b  = swz >> 9;

  const size_t kvbase = ((size_t)(b * H_ + h)) * NKV_ * HD_;
  const u16* Kh = Kg + kvbase;
  const u16* Vh = Vg + kvbase;
  const float* bkv = biaskv + b * NKV_;

  const int q0 = qt * 64 + w * 16;
  short8 aq[4];
  {
    const u16* qp = Q + (size_t)(b * NQ_ + q0 + lr) * D_ + h * HD_ + lg * 8;
#pragma unroll
    for (int ks = 0; ks < 4; ++ks) aq[ks] = *(const short8*)(qp + ks * 32);
  }

  f32x4 o[8] = {};
  float m[4], ln[4];
#pragma unroll
  for (int r = 0; r < 4; ++r) { m[r] = -1e30f; ln[r] = 0.f; }

  const int ntile = qt + 1;
  for (int kvt = 0; kvt < ntile; ++kvt) {
    const int kv0 = kvt * 64;
    // ---- stage K: 64x128 bf16, 256B rows = 16 chunks; glds covers 4 rows
#pragma unroll
    for (int i = 0; i < 4; ++i) {
      int r = w * 16 + i * 4 + lg;
      int c = lr ^ (r & 7);
      gload_lds16(Kh + (size_t)(kv0 + r) * HD_ + c * 8, (char*)Ks + (w * 16 + i * 4) * 256);
    }
    // ---- stage V transposed: lane = kv row -> conflict-free b16 writes
    {
      const u16* vp = Vh + (size_t)(kv0 + l) * HD_ + w * 32;
#pragma unroll
      for (int j = 0; j < 4; ++j) {
        short8 vv = *(const short8*)(vp + j * 8);
#pragma unroll
        for (int e = 0; e < 8; ++e)
          Vt[(w * 32 + j * 8 + e) * 72 + l] = (u16)vv[e];
      }
    }
    __syncthreads();

    // ---- S = Q K^T (16 x 64 per wave)
    f32x4 s[4];
#pragma unroll
    for (int nf = 0; nf < 4; ++nf) {
      f32x4 c = {};
#pragma unroll
      for (int ks = 0; ks < 4; ++ks) {
        int row = nf * 16 + lr;
        int pch = (ks * 4 + lg) ^ (row & 7);
        short8 bv = *(const short8*)((const char*)Ks + row * 256 + pch * 16);
        c = __builtin_amdgcn_mfma_f32_16x16x32_bf16(aq[ks], bv, c, 0, 0, 0);
      }
      s[nf] = c;
    }

    // ---- scale + tier/padding bias + causal (diagonal tile only)
    float sv[4][4];
#pragma unroll
    for (int nf = 0; nf < 4; ++nf) {
      int kv = kv0 + nf * 16 + lr;
      float bb = bkv[kv];
#pragma unroll
      for (int r = 0; r < 4; ++r) {
        float v = s[nf][r] * 0.08838834764831845f + bb;
        if (kvt == ntile - 1) {
          int q = q0 + lg * 4 + r;
          if (kv > q) v = -1e30f;
        }
        sv[nf][r] = v;
      }
    }

    // ---- online softmax: row reduce over 16 lanes (kv) within each lg group
    float pm[4];
#pragma unroll
    for (int r = 0; r < 4; ++r)
      pm[r] = fmaxf(fmaxf(sv[0][r], sv[1][r]), fmaxf(sv[2][r], sv[3][r]));
#pragma unroll
    for (int off = 1; off < 16; off <<= 1)
#pragma unroll
      for (int r = 0; r < 4; ++r)
        pm[r] = fmaxf(pm[r], __shfl_xor(pm[r], off, 64));

    float alpha[4], mn[4], ps[4];
#pragma unroll
    for (int r = 0; r < 4; ++r) {
      mn[r] = fmaxf(m[r], pm[r]);
      alpha[r] = __expf(m[r] - mn[r]);
      m[r] = mn[r];
      ps[r] = 0.f;
    }

    u16* Pw = &Ps[w][0];
#pragma unroll
    for (int nf = 0; nf < 4; ++nf)
#pragma unroll
      for (int r = 0; r < 4; ++r) {
        float p = __expf(sv[nf][r] - mn[r]);
        ps[r] += p;
        Pw[(lg * 4 + r) * 72 + nf * 16 + lr] = f2bf(p);
      }

#pragma unroll
    for (int off = 1; off < 16; off <<= 1)
#pragma unroll
      for (int r = 0; r < 4; ++r)
        ps[r] += __shfl_xor(ps[r], off, 64);

#pragma unroll
    for (int r = 0; r < 4; ++r) ln[r] = ln[r] * alpha[r] + ps[r];

#pragma unroll
    for (int cf = 0; cf < 8; ++cf)
#pragma unroll
      for (int r = 0; r < 4; ++r)
        o[cf][r] *= alpha[r];

    // ---- O += P @ V  (P from per-wave LDS, V from transposed tile)
#pragma unroll
    for (int ks = 0; ks < 2; ++ks) {
      short8 ap = *(const short8*)((const char*)Pw + lr * 144 + ks * 64 + lg * 16);
#pragma unroll
      for (int nf = 0; nf < 8; ++nf) {
        short8 bv = *(const short8*)((const char*)Vt + (nf * 16 + lr) * 144 + ks * 64 + lg * 16);
        o[nf] = __builtin_amdgcn_mfma_f32_16x16x32_bf16(ap, bv, o[nf], 0, 0, 0);
      }
    }
    __syncthreads();
  }

  // ---- normalize and write [B*NQ][D] bf16
#pragma unroll
  for (int r = 0; r < 4; ++r) {
    float inv = ln[r] > 0.f ? 1.f / ln[r] : 0.f;
    size_t row = (size_t)(b * NQ_ + q0 + lg * 4 + r);
#pragma unroll
    for (int nf = 0; nf < 8; ++nf)
      AO[row * D_ + h * HD_ + nf * 16 + lr] = f2bf(o[nf][r] * inv);
  }
}

// ---------------------------------------------------------------- launch
extern "C" void kernel_launch(void* const* d_in, const int* in_sizes, int n_in,
                              void* d_out, int out_size, void* d_ws, size_t ws_size,
                              hipStream_t stream) {
  const float* x     = (const float*)d_in[0];
  const float* k     = (const float*)d_in[1];
  const float* v     = (const float*)d_in[2];
  const int*   labels = (const int*)d_in[3];
  const unsigned char* mask = (const unsigned char*)d_in[4];
  const float* q_w   = (const float*)d_in[5];
  const float* q_b   = (const float*)d_in[6];
  const float* out_w = (const float*)d_in[7];
  const float* out_b = (const float*)d_in[8];
  const float* tbias = (const float*)d_in[9];

  char* ws = (char*)d_ws;
  u16* x_bf  = (u16*)(ws + 0);          // 16.8MB
  u16* qw_bf = (u16*)(ws + 16777216);   // 8.4MB
  u16* ow_bf = (u16*)(ws + 25165824);   // 8.4MB
  u16* k_bf  = (u16*)(ws + 33554432);   // 16.8MB
  u16* v_bf  = (u16*)(ws + 50331648);   // 16.8MB
  u16* q_bf  = (u16*)(ws + 67108864);   // 16.8MB
  u16* ao_bf = (u16*)(ws + 83886080);   // 16.8MB
  float* bkv = (float*)(ws + 100663296);// 16KB

  cast_bf16<<<4096, 256, 0, stream>>>(x,     x_bf,  1048576);
  cast_bf16<<<2048, 256, 0, stream>>>(q_w,   qw_bf,  524288);
  cast_bf16<<<2048, 256, 0, stream>>>(out_w, ow_bf,  524288);
  cast_bf16<<<4096, 256, 0, stream>>>(k,     k_bf,  1048576);
  cast_bf16<<<4096, 256, 0, stream>>>(v,     v_bf,  1048576);
  build_bias<<<16, 256, 0, stream>>>(labels, mask, tbias, bkv, B_ * NKV_);

  gemm_bt<1><<<512, 256, 0, stream>>>(x_bf, qw_bf, q_b, (void*)q_bf, MM_, D_, D_);
  attn_fwd<<<1024, 256, 0, stream>>>(q_bf, k_bf, v_bf, bkv, ao_bf);
  gemm_bt<0><<<512, 256, 0, stream>>>(ao_bf, ow_bf, out_b, d_out, MM_, D_, D_);
}

// Round 2
// 398.108 us; speedup vs baseline: 1.0148x; 1.0148x over previous
//
#include <hip/hip_runtime.h>
#include <stdint.h>

typedef unsigned short u16;
typedef __attribute__((ext_vector_type(8))) short short8;
typedef __attribute__((ext_vector_type(4))) float f32x4;
typedef __attribute__((ext_vector_type(4))) uint32_t u32x4;

#define B_   2
#define NQ_  2048
#define NKV_ 2048
#define D_   2048
#define H_   16
#define HD_  128
#define MM_  (B_*NQ_)   // 4096
#define LOG2E 1.4426950408889634f
#define QSCALE (0.08838834764831845f * 1.4426950408889634f)

// round-to-nearest-even f32 -> bf16
__device__ __forceinline__ u16 f2bf(float f) {
  uint32_t u = __float_as_uint(f);
  u += 0x7fffu + ((u >> 16) & 1u);
  return (u16)(u >> 16);
}

// async global->LDS, 16B per lane; LDS dest is wave-uniform base + lane*16
__device__ __forceinline__ void gload_lds16(const void* g, void* l) {
  __builtin_amdgcn_global_load_lds(
      (const __attribute__((address_space(1))) void*)g,
      (__attribute__((address_space(3))) void*)l, 16, 0, 0);
}

// ---------------------------------------------------------------- casts
__global__ __launch_bounds__(256) void cast_bf16(const float* __restrict__ src,
                                                 u16* __restrict__ dst, int n8) {
  int i = blockIdx.x * 256 + threadIdx.x;
  if (i >= n8) return;
  const float4* s = (const float4*)src + (size_t)i * 2;
  float4 a = s[0], b = s[1];
  short8 o;
  o[0] = (short)f2bf(a.x); o[1] = (short)f2bf(a.y);
  o[2] = (short)f2bf(a.z); o[3] = (short)f2bf(a.w);
  o[4] = (short)f2bf(b.x); o[5] = (short)f2bf(b.y);
  o[6] = (short)f2bf(b.z); o[7] = (short)f2bf(b.w);
  *((short8*)dst + i) = o;
}

// bias table in log2 domain (exp2-direct softmax)
__global__ __launch_bounds__(256) void build_bias(const int* __restrict__ labels,
                                                  const unsigned char* __restrict__ mask,
                                                  const float* __restrict__ tb,
                                                  float* __restrict__ out, int n) {
  int i = blockIdx.x * 256 + threadIdx.x;
  if (i < n) out[i] = mask[i] ? -1e30f : tb[labels[i]] * LOG2E;
}

// ---------------------------------------------------------------- GEMM C = (A @ W^T + bias) * escale
template<int OUT_BF16>
__global__ __launch_bounds__(256, 2) void gemm_bt(
    const u16* __restrict__ A, const u16* __restrict__ W,
    const float* __restrict__ bias, void* __restrict__ Cout,
    int M, int N, int K, float escale)
{
  __shared__ u16 As[128 * 64];
  __shared__ u16 Bs[128 * 64];
  const int tid = threadIdx.x;
  const int w = tid >> 6, l = tid & 63;
  const int lr = l & 15, lg = l >> 4;
  const int nbn = N >> 7;
  const int nwg = gridDim.x;
  int bid = blockIdx.x;
  int swz = (bid & 7) * (nwg >> 3) + (bid >> 3);   // bijective: nwg % 8 == 0
  const int bm = swz / nbn, bn = swz % nbn;
  const int wm = w >> 1, wn = w & 1;

  f32x4 acc[4][4] = {};

  const int sr = w * 32 + (l >> 3);
  const int sc = l & 7;

  for (int kt = 0; kt < K; kt += 64) {
#pragma unroll
    for (int i = 0; i < 4; ++i) {
      int r = sr + i * 8;
      int gc = kt + ((sc ^ (r & 7)) << 3);
      gload_lds16(A + (size_t)(bm * 128 + r) * K + gc, (char*)As + (w * 32 + i * 8) * 128);
      gload_lds16(W + (size_t)(bn * 128 + r) * K + gc, (char*)Bs + (w * 32 + i * 8) * 128);
    }
    __syncthreads();
#pragma unroll
    for (int ks = 0; ks < 2; ++ks) {
      short8 av[4], bv[4];
#pragma unroll
      for (int mf = 0; mf < 4; ++mf) {
        int row = wm * 64 + mf * 16 + lr;
        int pch = (ks * 4 + lg) ^ (row & 7);
        av[mf] = *(const short8*)((const char*)As + row * 128 + pch * 16);
      }
#pragma unroll
      for (int nf = 0; nf < 4; ++nf) {
        int row = wn * 64 + nf * 16 + lr;
        int pch = (ks * 4 + lg) ^ (row & 7);
        bv[nf] = *(const short8*)((const char*)Bs + row * 128 + pch * 16);
      }
#pragma unroll
      for (int mf = 0; mf < 4; ++mf)
#pragma unroll
        for (int nf = 0; nf < 4; ++nf)
          acc[mf][nf] = __builtin_amdgcn_mfma_f32_16x16x32_bf16(av[mf], bv[nf], acc[mf][nf], 0, 0, 0);
    }
    __syncthreads();
  }

  const int row0 = bm * 128 + wm * 64;
  const int col0 = bn * 128 + wn * 64;
#pragma unroll
  for (int nf = 0; nf < 4; ++nf) {
    int col = col0 + nf * 16 + lr;
    float bb = bias[col];
#pragma unroll
    for (int mf = 0; mf < 4; ++mf) {
#pragma unroll
      for (int r = 0; r < 4; ++r) {
        size_t row = (size_t)(row0 + mf * 16 + lg * 4 + r);
        float vv = (acc[mf][nf][r] + bb) * escale;
        if (OUT_BF16) ((u16*)Cout)[row * N + col] = f2bf(vv);
        else          ((float*)Cout)[row * N + col] = vv;
      }
    }
  }
}

// ---------------------------------------------------------------- attention
// Swapped QK^T: mfma(K_frag, Q_frag) -> S^T; each lane holds 16 P values for
// one q row (q = q0 + lr), kv = nf*16 + lg*4 + r. Softmax fully in-register.
// P -> A-fragment redistribution via 8 shfls (verified vs old LDS layout).
__device__ __forceinline__ void softmax16(
    const f32x4 s[4], const f32x4 bias4[4], bool diag, int qrow, int kv0,
    int lr, int lg, float& m, float& d, f32x4 o[8], short8 ap[2])
{
  float sv[4][4];
  float pm = -3e38f;
#pragma unroll
  for (int nf = 0; nf < 4; ++nf)
#pragma unroll
    for (int r = 0; r < 4; ++r) {
      float v = s[nf][r] + bias4[nf][r];
      if (diag) {
        int kv = kv0 + nf * 16 + lg * 4 + r;
        if (kv > qrow) v = -1e30f;
      }
      sv[nf][r] = v;
      pm = fmaxf(pm, v);
    }
  pm = fmaxf(pm, __shfl_xor(pm, 16));
  pm = fmaxf(pm, __shfl_xor(pm, 32));
  float mn = fmaxf(m, pm);
  float al = __builtin_exp2f(m - mn);
  m = mn;
  float ps = 0.f;
  uint32_t pk0[4], pk1[4];   // pk0[nf] = pack(r0,r1), pk1[nf] = pack(r2,r3)
#pragma unroll
  for (int nf = 0; nf < 4; ++nf) {
    float p0 = __builtin_exp2f(sv[nf][0] - mn);
    float p1 = __builtin_exp2f(sv[nf][1] - mn);
    float p2 = __builtin_exp2f(sv[nf][2] - mn);
    float p3 = __builtin_exp2f(sv[nf][3] - mn);
    ps += (p0 + p1) + (p2 + p3);
    pk0[nf] = (uint32_t)f2bf(p0) | ((uint32_t)f2bf(p1) << 16);
    pk1[nf] = (uint32_t)f2bf(p2) | ((uint32_t)f2bf(p3) << 16);
  }
  ps += __shfl_xor(ps, 16);
  ps += __shfl_xor(ps, 32);
  d = d * al + ps;
  // rescale O (accumulator lives in r-space: q = q0 + lg*4 + r)
  float alr[4];
#pragma unroll
  for (int r = 0; r < 4; ++r) alr[r] = __shfl(al, lg * 4 + r);
#pragma unroll
  for (int nf = 0; nf < 8; ++nf) {
    o[nf][0] *= alr[0]; o[nf][1] *= alr[1];
    o[nf][2] *= alr[2]; o[nf][3] *= alr[3];
  }
  // P -> A-fragment: ap[ks] elem e = P[q=lr][kv = 32ks + 8lg + e]
  // instruction i: lanes lg<2 fetch word i, lg>=2 fetch word i^2.
#pragma unroll
  for (int ks = 0; ks < 2; ++ks) {
    uint32_t rr[4];
#pragma unroll
    for (int i = 0; i < 4; ++i) {
      // source contribution: nfsel = 2ks if (lg&1)==(i>>1) else 2ks+1; pair = i&1
      uint32_t c0 = ((lg & 1) == (i >> 1)) ? pk0[2 * ks] : pk0[2 * ks + 1];
      uint32_t c1 = ((lg & 1) == (i >> 1)) ? pk1[2 * ks] : pk1[2 * ks + 1];
      uint32_t contrib = (i & 1) ? c1 : c0;
      int srclg = (lg & 1) * 2 + ((i >> 1) ^ (lg >> 1));
      rr[i] = (uint32_t)__shfl((int)contrib, lr + 16 * srclg);
    }
    u32x4 t4;
    t4[0] = (lg & 2) ? rr[2] : rr[0];
    t4[1] = (lg & 2) ? rr[3] : rr[1];
    t4[2] = (lg & 2) ? rr[0] : rr[2];
    t4[3] = (lg & 2) ? rr[1] : rr[3];
    ap[ks] = __builtin_bit_cast(short8, t4);
  }
}

template<int WA>
__device__ __forceinline__ void compute_tile(
    const u16* __restrict__ ksb, const u16* __restrict__ vtb,
    const short8 aqB[4], const short8 aqA[4],
    f32x4 oB[8], f32x4 oA[8],
    float& mB, float& dB, float& mA, float& dA,
    const f32x4 bias4[4], bool diagB, bool diagA,
    int qrowB, int qrowA, int kv0, int lr, int lg)
{
  f32x4 sB[4] = {}, sA[4] = {};
  __builtin_amdgcn_s_setprio(1);
#pragma unroll
  for (int nf = 0; nf < 4; ++nf) {
#pragma unroll
    for (int ks = 0; ks < 4; ++ks) {
      int row = nf * 16 + lr;
      int pch = (ks * 4 + lg) ^ (row & 7);
      short8 bk = *(const short8*)((const char*)ksb + row * 256 + pch * 16);
      sB[nf] = __builtin_amdgcn_mfma_f32_16x16x32_bf16(bk, aqB[ks], sB[nf], 0, 0, 0);
      if (WA) sA[nf] = __builtin_amdgcn_mfma_f32_16x16x32_bf16(bk, aqA[ks], sA[nf], 0, 0, 0);
    }
  }
  __builtin_amdgcn_s_setprio(0);

  short8 apB[2], apA[2];
  softmax16(sB, bias4, diagB, qrowB, kv0, lr, lg, mB, dB, oB, apB);
  if (WA) softmax16(sA, bias4, diagA, qrowA, kv0, lr, lg, mA, dA, oA, apA);

  __builtin_amdgcn_s_setprio(1);
#pragma unroll
  for (int ks = 0; ks < 2; ++ks) {
#pragma unroll
    for (int nf = 0; nf < 8; ++nf) {
      short8 bv = *(const short8*)((const char*)vtb + (nf * 16 + lr) * 144 + ks * 64 + lg * 16);
      oB[nf] = __builtin_amdgcn_mfma_f32_16x16x32_bf16(apB[ks], bv, oB[nf], 0, 0, 0);
      if (WA) oA[nf] = __builtin_amdgcn_mfma_f32_16x16x32_bf16(apA[ks], bv, oA[nf], 0, 0, 0);
    }
  }
  __builtin_amdgcn_s_setprio(0);
}

// block = (bh, pi): q-tiles qtA=pi, qtB=31-pi (33 units each, perfect balance).
// 512 blocks, 4 waves x 16 q rows per tile. Double-buffered K/V, 1 barrier/tile.
__global__ __launch_bounds__(256, 2) void attn_fwd(
    const u16* __restrict__ Q, const u16* __restrict__ Kg,
    const u16* __restrict__ Vg, const float* __restrict__ biaskv,
    u16* __restrict__ AO)
{
  __shared__ u16 Ks[2][64 * 128];
  __shared__ u16 Vt[2][128 * 72];

  const int tid = threadIdx.x;
  const int w = tid >> 6, l = tid & 63;
  const int lr = l & 15, lg = l >> 4;

  const int bid = blockIdx.x;
  const int bh = bid & 31, pi = bid >> 5;   // same-bh blocks share an XCD (bid%8=bh%8)
  const int b = bh >> 4, h = bh & 15;
  const int qtA = pi, qtB = 31 - pi;

  const size_t kvbase = ((size_t)bh) * NKV_ * HD_;
  const u16* Kh = Kg + kvbase;
  const u16* Vh = Vg + kvbase;
  const float* bkv = biaskv + b * NKV_;

  const int q0A = qtA * 64 + w * 16;
  const int q0B = qtB * 64 + w * 16;

  short8 aqA[4], aqB[4];
  {
    const u16* qpA = Q + (size_t)(b * NQ_ + q0A + lr) * D_ + h * HD_ + lg * 8;
    const u16* qpB = Q + (size_t)(b * NQ_ + q0B + lr) * D_ + h * HD_ + lg * 8;
#pragma unroll
    for (int ks = 0; ks < 4; ++ks) {
      aqA[ks] = *(const short8*)(qpA + ks * 32);
      aqB[ks] = *(const short8*)(qpB + ks * 32);
    }
  }

  f32x4 oA[8] = {}, oB[8] = {};
  float mA = -1e30f, mB = -1e30f, dA = 0.f, dB = 0.f;

  short8 vv[4];
  // ---- prologue: stage tile 0 -> buf 0
  {
#pragma unroll
    for (int i = 0; i < 4; ++i) {
      int r = w * 16 + i * 4 + lg;
      int c = lr ^ (r & 7);
      gload_lds16(Kh + (size_t)r * HD_ + c * 8, (char*)&Ks[0][0] + (w * 16 + i * 4) * 256);
    }
    const u16* vp = Vh + (size_t)l * HD_ + w * 32;
#pragma unroll
    for (int j = 0; j < 4; ++j) vv[j] = *(const short8*)(vp + j * 8);
#pragma unroll
    for (int j = 0; j < 4; ++j)
#pragma unroll
      for (int e = 0; e < 8; ++e)
        Vt[0][(w * 32 + j * 8 + e) * 72 + l] = (u16)vv[j][e];
  }
  __syncthreads();

  int cur = 0;
  for (int kvt = 0; kvt <= qtB; ++kvt) {
    const int kv0 = kvt * 64;
    const bool haveNext = (kvt < qtB);
    if (haveNext) {
      const int kvn = kv0 + 64;
#pragma unroll
      for (int i = 0; i < 4; ++i) {
        int r = w * 16 + i * 4 + lg;
        int c = lr ^ (r & 7);
        gload_lds16(Kh + (size_t)(kvn + r) * HD_ + c * 8,
                    (char*)&Ks[cur ^ 1][0] + (w * 16 + i * 4) * 256);
      }
      const u16* vp = Vh + (size_t)(kvn + l) * HD_ + w * 32;
#pragma unroll
      for (int j = 0; j < 4; ++j) vv[j] = *(const short8*)(vp + j * 8);
    }

    f32x4 bias4[4];
#pragma unroll
    for (int nf = 0; nf < 4; ++nf)
      bias4[nf] = *(const f32x4*)(bkv + kv0 + nf * 16 + lg * 4);

    if (kvt <= qtA)
      compute_tile<1>(&Ks[cur][0], &Vt[cur][0], aqB, aqA, oB, oA, mB, dB, mA, dA,
                      bias4, kvt == qtB, kvt == qtA, q0B + lr, q0A + lr, kv0, lr, lg);
    else
      compute_tile<0>(&Ks[cur][0], &Vt[cur][0], aqB, aqA, oB, oA, mB, dB, mA, dA,
                      bias4, kvt == qtB, false, q0B + lr, q0A + lr, kv0, lr, lg);

    if (haveNext) {
#pragma unroll
      for (int j = 0; j < 4; ++j)
#pragma unroll
        for (int e = 0; e < 8; ++e)
          Vt[cur ^ 1][(w * 32 + j * 8 + e) * 72 + l] = (u16)vv[j][e];
    }
    __syncthreads();
    cur ^= 1;
  }

  // ---- epilogue
  float dvB[4], dvA[4];
#pragma unroll
  for (int r = 0; r < 4; ++r) {
    dvB[r] = __shfl(dB, lg * 4 + r);
    dvA[r] = __shfl(dA, lg * 4 + r);
  }
#pragma unroll
  for (int r = 0; r < 4; ++r) {
    float inv = 1.f / dvB[r];
    size_t row = (size_t)(b * NQ_ + q0B + lg * 4 + r);
#pragma unroll
    for (int nf = 0; nf < 8; ++nf)
      AO[row * D_ + h * HD_ + nf * 16 + lr] = f2bf(oB[nf][r] * inv);
  }
#pragma unroll
  for (int r = 0; r < 4; ++r) {
    float inv = 1.f / dvA[r];
    size_t row = (size_t)(b * NQ_ + q0A + lg * 4 + r);
#pragma unroll
    for (int nf = 0; nf < 8; ++nf)
      AO[row * D_ + h * HD_ + nf * 16 + lr] = f2bf(oA[nf][r] * inv);
  }
}

// ---------------------------------------------------------------- launch
extern "C" void kernel_launch(void* const* d_in, const int* in_sizes, int n_in,
                              void* d_out, int out_size, void* d_ws, size_t ws_size,
                              hipStream_t stream) {
  const float* x     = (const float*)d_in[0];
  const float* k     = (const float*)d_in[1];
  const float* v     = (const float*)d_in[2];
  const int*   labels = (const int*)d_in[3];
  const unsigned char* mask = (const unsigned char*)d_in[4];
  const float* q_w   = (const float*)d_in[5];
  const float* q_b   = (const float*)d_in[6];
  const float* out_w = (const float*)d_in[7];
  const float* out_b = (const float*)d_in[8];
  const float* tbias = (const float*)d_in[9];

  char* ws = (char*)d_ws;
  u16* x_bf  = (u16*)(ws + 0);          // 16.8MB
  u16* qw_bf = (u16*)(ws + 16777216);   // 8.4MB
  u16* ow_bf = (u16*)(ws + 25165824);   // 8.4MB
  u16* k_bf  = (u16*)(ws + 33554432);   // 16.8MB
  u16* v_bf  = (u16*)(ws + 50331648);   // 16.8MB
  u16* q_bf  = (u16*)(ws + 67108864);   // 16.8MB
  u16* ao_bf = (u16*)(ws + 83886080);   // 16.8MB
  float* bkv = (float*)(ws + 100663296);// 16KB

  cast_bf16<<<4096, 256, 0, stream>>>(x,     x_bf,  1048576);
  cast_bf16<<<2048, 256, 0, stream>>>(q_w,   qw_bf,  524288);
  cast_bf16<<<2048, 256, 0, stream>>>(out_w, ow_bf,  524288);
  cast_bf16<<<4096, 256, 0, stream>>>(k,     k_bf,  1048576);
  cast_bf16<<<4096, 256, 0, stream>>>(v,     v_bf,  1048576);
  build_bias<<<16, 256, 0, stream>>>(labels, mask, tbias, bkv, B_ * NKV_);

  gemm_bt<1><<<512, 256, 0, stream>>>(x_bf, qw_bf, q_b, (void*)q_bf, MM_, D_, D_, QSCALE);
  attn_fwd<<<512, 256, 0, stream>>>(q_bf, k_bf, v_bf, bkv, ao_bf);
  gemm_bt<0><<<512, 256, 0, stream>>>(ao_bf, ow_bf, out_b, d_out, MM_, D_, D_, 1.0f);
}

// Round 3
// 391.455 us; speedup vs baseline: 1.0320x; 1.0170x over previous
//
#include <hip/hip_runtime.h>
#include <stdint.h>

typedef unsigned short u16;
typedef __attribute__((ext_vector_type(8))) short short8;
typedef __attribute__((ext_vector_type(4))) float f32x4;
typedef __attribute__((ext_vector_type(4))) uint32_t u32x4;

#define B_   2
#define NQ_  2048
#define NKV_ 2048
#define D_   2048
#define H_   16
#define HD_  128
#define MM_  (B_*NQ_)   // 4096
#define LOG2E 1.4426950408889634f
#define QSCALE (0.08838834764831845f * 1.4426950408889634f)

// round-to-nearest-even f32 -> bf16 (scalar path)
__device__ __forceinline__ u16 f2bf(float f) {
  uint32_t u = __float_as_uint(f);
  u += 0x7fffu + ((u >> 16) & 1u);
  return (u16)(u >> 16);
}

// packed f32x2 -> bf16x2 (T12: no builtin on gfx950, inline asm)
__device__ __forceinline__ uint32_t cvtpk(float lo, float hi) {
  uint32_t r;
  asm("v_cvt_pk_bf16_f32 %0, %1, %2" : "=v"(r) : "v"(lo), "v"(hi));
  return r;
}

// async global->LDS, 16B per lane; LDS dest is wave-uniform base + lane*16
__device__ __forceinline__ void gload_lds16(const void* g, void* l) {
  __builtin_amdgcn_global_load_lds(
      (const __attribute__((address_space(1))) void*)g,
      (__attribute__((address_space(3))) void*)l, 16, 0, 0);
}

// ---------------------------------------------------------------- fused casts
// one launch casts all five f32 tensors to bf16 (region if-chain, 8 elems/thread)
__global__ __launch_bounds__(256) void cast_all(
    const float* __restrict__ x,  const float* __restrict__ qw,
    const float* __restrict__ ow, const float* __restrict__ k,
    const float* __restrict__ v,
    u16* __restrict__ xo, u16* __restrict__ qwo, u16* __restrict__ owo,
    u16* __restrict__ ko, u16* __restrict__ vo)
{
  int i = blockIdx.x * 256 + threadIdx.x;   // in units of 8 floats
  const float* s; u16* d; int off;
  if      (i < 1048576) { s = x;  d = xo;  off = i; }
  else if (i < 1572864) { s = qw; d = qwo; off = i - 1048576; }
  else if (i < 2097152) { s = ow; d = owo; off = i - 1572864; }
  else if (i < 3145728) { s = k;  d = ko;  off = i - 2097152; }
  else                  { s = v;  d = vo;  off = i - 3145728; }
  const float4* sp = (const float4*)s + (size_t)off * 2;
  float4 a = sp[0], b = sp[1];
  short8 o;
  o[0] = (short)f2bf(a.x); o[1] = (short)f2bf(a.y);
  o[2] = (short)f2bf(a.z); o[3] = (short)f2bf(a.w);
  o[4] = (short)f2bf(b.x); o[5] = (short)f2bf(b.y);
  o[6] = (short)f2bf(b.z); o[7] = (short)f2bf(b.w);
  *((short8*)d + off) = o;
}

// bias table in log2 domain (exp2-direct softmax)
__global__ __launch_bounds__(256) void build_bias(const int* __restrict__ labels,
                                                  const unsigned char* __restrict__ mask,
                                                  const float* __restrict__ tb,
                                                  float* __restrict__ out, int n) {
  int i = blockIdx.x * 256 + threadIdx.x;
  if (i < n) out[i] = mask[i] ? -1e30f : tb[labels[i]] * LOG2E;
}

// ---------------------------------------------------------------- GEMM C = (A @ W^T + bias) * escale
// 128x128 tile, BK=64, 4 waves (2x2), 16x16x32 MFMA.
// T3-minimum 2-phase: LDS dbuf, STAGE(t+1) issued BEFORE compute(t),
// one vmcnt(0)+barrier per K-tile (the __syncthreads drain).
template<int OUT_BF16>
__global__ __launch_bounds__(256, 2) void gemm_bt(
    const u16* __restrict__ A, const u16* __restrict__ W,
    const float* __restrict__ bias, void* __restrict__ Cout,
    int M, int N, int K, float escale)
{
  __shared__ u16 As[2][128 * 64];
  __shared__ u16 Bs[2][128 * 64];
  const int tid = threadIdx.x;
  const int w = tid >> 6, l = tid & 63;
  const int lr = l & 15, lg = l >> 4;
  const int nbn = N >> 7;
  const int nwg = gridDim.x;
  int bid = blockIdx.x;
  int swz = (bid & 7) * (nwg >> 3) + (bid >> 3);   // bijective: nwg % 8 == 0
  const int bm = swz / nbn, bn = swz % nbn;
  const int wm = w >> 1, wn = w & 1;

  f32x4 acc[4][4] = {};

  const int sr = w * 32 + (l >> 3);
  const int sc = l & 7;

  auto stage = [&](int buf, int kt) {
#pragma unroll
    for (int i = 0; i < 4; ++i) {
      int r = sr + i * 8;
      int gc = kt + ((sc ^ (r & 7)) << 3);
      gload_lds16(A + (size_t)(bm * 128 + r) * K + gc,
                  (char*)&As[buf][0] + (w * 32 + i * 8) * 128);
      gload_lds16(W + (size_t)(bn * 128 + r) * K + gc,
                  (char*)&Bs[buf][0] + (w * 32 + i * 8) * 128);
    }
  };

  auto compute = [&](int buf) {
#pragma unroll
    for (int ks = 0; ks < 2; ++ks) {
      short8 av[4], bv[4];
#pragma unroll
      for (int mf = 0; mf < 4; ++mf) {
        int row = wm * 64 + mf * 16 + lr;
        int pch = (ks * 4 + lg) ^ (row & 7);
        av[mf] = *(const short8*)((const char*)&As[buf][0] + row * 128 + pch * 16);
      }
#pragma unroll
      for (int nf = 0; nf < 4; ++nf) {
        int row = wn * 64 + nf * 16 + lr;
        int pch = (ks * 4 + lg) ^ (row & 7);
        bv[nf] = *(const short8*)((const char*)&Bs[buf][0] + row * 128 + pch * 16);
      }
#pragma unroll
      for (int mf = 0; mf < 4; ++mf)
#pragma unroll
        for (int nf = 0; nf < 4; ++nf)
          acc[mf][nf] = __builtin_amdgcn_mfma_f32_16x16x32_bf16(av[mf], bv[nf], acc[mf][nf], 0, 0, 0);
    }
  };

  stage(0, 0);
  __syncthreads();
  int cur = 0;
  const int NT = K >> 6;
  for (int t = 0; t < NT - 1; ++t) {
    stage(cur ^ 1, (t + 1) << 6);   // prefetch next K-tile (overlaps compute)
    compute(cur);
    __syncthreads();                // vmcnt(0) drain: next tile landed
    cur ^= 1;
  }
  compute(cur);

  const int row0 = bm * 128 + wm * 64;
  const int col0 = bn * 128 + wn * 64;
#pragma unroll
  for (int nf = 0; nf < 4; ++nf) {
    int col = col0 + nf * 16 + lr;
    float bb = bias[col];
#pragma unroll
    for (int mf = 0; mf < 4; ++mf) {
#pragma unroll
      for (int r = 0; r < 4; ++r) {
        size_t row = (size_t)(row0 + mf * 16 + lg * 4 + r);
        float vv = (acc[mf][nf][r] + bb) * escale;
        if (OUT_BF16) ((u16*)Cout)[row * N + col] = f2bf(vv);
        else          ((float*)Cout)[row * N + col] = vv;
      }
    }
  }
}

// ---------------------------------------------------------------- attention
// Swapped QK^T: mfma(K_frag, Q_frag) -> S^T; lane holds 16 P values for one
// q row (q = q0 + lr). In-register softmax, defer-max (THR=8, log2 domain),
// cvt_pk bf16 packing, P->A-frag via 8 shfls.
__device__ __forceinline__ void softmax16(
    const f32x4 s[4], const f32x4 bias4[4], bool diag, int qrow, int kv0,
    int lr, int lg, float& m, float& d, f32x4 o[8], short8 ap[2])
{
  float sv[4][4];
  float pm = -3e38f;
#pragma unroll
  for (int nf = 0; nf < 4; ++nf)
#pragma unroll
    for (int r = 0; r < 4; ++r) {
      float v = s[nf][r] + bias4[nf][r];
      if (diag) {
        int kv = kv0 + nf * 16 + lg * 4 + r;
        if (kv > qrow) v = -1e30f;
      }
      sv[nf][r] = v;
      pm = fmaxf(pm, v);
    }
  pm = fmaxf(pm, __shfl_xor(pm, 16));
  pm = fmaxf(pm, __shfl_xor(pm, 32));
  // defer-max (T13): only rescale when some row grew past THR=8 (wave-uniform)
  if (__any(pm > m + 8.f)) {
    float mn = fmaxf(m, pm);
    float al = __builtin_exp2f(m - mn);
    m = mn;
    d *= al;
    float alr[4];
#pragma unroll
    for (int r = 0; r < 4; ++r) alr[r] = __shfl(al, lg * 4 + r);
#pragma unroll
    for (int nf = 0; nf < 8; ++nf) {
      o[nf][0] *= alr[0]; o[nf][1] *= alr[1];
      o[nf][2] *= alr[2]; o[nf][3] *= alr[3];
    }
  }
  float ps = 0.f;
  uint32_t pk0[4], pk1[4];   // pk0[nf] = pack(r0,r1), pk1[nf] = pack(r2,r3)
#pragma unroll
  for (int nf = 0; nf < 4; ++nf) {
    float p0 = __builtin_exp2f(sv[nf][0] - m);
    float p1 = __builtin_exp2f(sv[nf][1] - m);
    float p2 = __builtin_exp2f(sv[nf][2] - m);
    float p3 = __builtin_exp2f(sv[nf][3] - m);
    ps += (p0 + p1) + (p2 + p3);
    pk0[nf] = cvtpk(p0, p1);
    pk1[nf] = cvtpk(p2, p3);
  }
  ps += __shfl_xor(ps, 16);
  ps += __shfl_xor(ps, 32);
  d += ps;
  // P -> A-fragment: ap[ks] elem e = P[q=lr][kv = 32ks + 8lg + e]
#pragma unroll
  for (int ks = 0; ks < 2; ++ks) {
    uint32_t rr[4];
#pragma unroll
    for (int i = 0; i < 4; ++i) {
      uint32_t c0 = ((lg & 1) == (i >> 1)) ? pk0[2 * ks] : pk0[2 * ks + 1];
      uint32_t c1 = ((lg & 1) == (i >> 1)) ? pk1[2 * ks] : pk1[2 * ks + 1];
      uint32_t contrib = (i & 1) ? c1 : c0;
      int srclg = (lg & 1) * 2 + ((i >> 1) ^ (lg >> 1));
      rr[i] = (uint32_t)__shfl((int)contrib, lr + 16 * srclg);
    }
    u32x4 t4;
    t4[0] = (lg & 2) ? rr[2] : rr[0];
    t4[1] = (lg & 2) ? rr[3] : rr[1];
    t4[2] = (lg & 2) ? rr[0] : rr[2];
    t4[3] = (lg & 2) ? rr[1] : rr[3];
    ap[ks] = __builtin_bit_cast(short8, t4);
  }
}

template<int WA>
__device__ __forceinline__ void compute_tile(
    const u16* __restrict__ ksb, const u16* __restrict__ vtb,
    const short8 aqB[4], const short8 aqA[4],
    f32x4 oB[8], f32x4 oA[8],
    float& mB, float& dB, float& mA, float& dA,
    const f32x4 bias4[4], bool diagB, bool diagA,
    int qrowB, int qrowA, int kv0, int lr, int lg)
{
  f32x4 sB[4] = {}, sA[4] = {};
  __builtin_amdgcn_s_setprio(1);
#pragma unroll
  for (int nf = 0; nf < 4; ++nf) {
#pragma unroll
    for (int ks = 0; ks < 4; ++ks) {
      int row = nf * 16 + lr;
      int pch = (ks * 4 + lg) ^ (row & 7);
      short8 bk = *(const short8*)((const char*)ksb + row * 256 + pch * 16);
      sB[nf] = __builtin_amdgcn_mfma_f32_16x16x32_bf16(bk, aqB[ks], sB[nf], 0, 0, 0);
      if (WA) sA[nf] = __builtin_amdgcn_mfma_f32_16x16x32_bf16(bk, aqA[ks], sA[nf], 0, 0, 0);
    }
  }
  __builtin_amdgcn_s_setprio(0);

  short8 apB[2], apA[2];
  softmax16(sB, bias4, diagB, qrowB, kv0, lr, lg, mB, dB, oB, apB);
  if (WA) softmax16(sA, bias4, diagA, qrowA, kv0, lr, lg, mA, dA, oA, apA);

  __builtin_amdgcn_s_setprio(1);
#pragma unroll
  for (int ks = 0; ks < 2; ++ks) {
#pragma unroll
    for (int nf = 0; nf < 8; ++nf) {
      int rowv = nf * 16 + lr;
      short8 bv = *(const short8*)(vtb + rowv * 64 + (((ks * 4 + lg) ^ (lr & 7)) << 3));
      oB[nf] = __builtin_amdgcn_mfma_f32_16x16x32_bf16(apB[ks], bv, oB[nf], 0, 0, 0);
      if (WA) oA[nf] = __builtin_amdgcn_mfma_f32_16x16x32_bf16(apA[ks], bv, oA[nf], 0, 0, 0);
    }
  }
  __builtin_amdgcn_s_setprio(0);
}

// block = (bh, pi): q-tiles qtA=pi, qtB=31-pi (33 units each, perfect balance).
// 512 blocks, 4 waves x 16 q rows per tile. Double-buffered K/V, 1 barrier/tile.
__global__ __launch_bounds__(256, 2) void attn_fwd(
    const u16* __restrict__ Q, const u16* __restrict__ Kg,
    const u16* __restrict__ Vg, const float* __restrict__ biaskv,
    u16* __restrict__ AO)
{
  __shared__ u16 Ks[2][64 * 128];   // chunk-XOR swizzled (via source perm)
  __shared__ u16 Vt[2][128 * 64];   // V^T, chunk-XOR swizzled

  const int tid = threadIdx.x;
  const int w = tid >> 6, l = tid & 63;
  const int lr = l & 15, lg = l >> 4;

  const int bid = blockIdx.x;
  const int bh = bid & 31, pi = bid >> 5;   // same-bh blocks share an XCD
  const int b = bh >> 4, h = bh & 15;
  const int qtA = pi, qtB = 31 - pi;

  const size_t kvbase = ((size_t)bh) * NKV_ * HD_;
  const u16* Kh = Kg + kvbase;
  const u16* Vh = Vg + kvbase;
  const float* bkv = biaskv + b * NKV_;

  const int q0A = qtA * 64 + w * 16;
  const int q0B = qtB * 64 + w * 16;

  short8 aqA[4], aqB[4];
  {
    const u16* qpA = Q + (size_t)(b * NQ_ + q0A + lr) * D_ + h * HD_ + lg * 8;
    const u16* qpB = Q + (size_t)(b * NQ_ + q0B + lr) * D_ + h * HD_ + lg * 8;
#pragma unroll
    for (int ks = 0; ks < 4; ++ks) {
      aqA[ks] = *(const short8*)(qpA + ks * 32);
      aqB[ks] = *(const short8*)(qpB + ks * 32);
    }
  }

  f32x4 oA[8] = {}, oB[8] = {};
  float mA = -1e30f, mB = -1e30f, dA = 0.f, dB = 0.f;

  short8 vv[4];
  // ---- prologue: stage tile 0 -> buf 0
  {
#pragma unroll
    for (int i = 0; i < 4; ++i) {
      int r = w * 16 + i * 4 + lg;
      int c = lr ^ (r & 7);
      gload_lds16(Kh + (size_t)r * HD_ + c * 8, (char*)&Ks[0][0] + (w * 16 + i * 4) * 256);
    }
    const u16* vp = Vh + (size_t)l * HD_ + w * 32;
#pragma unroll
    for (int j = 0; j < 4; ++j) vv[j] = *(const short8*)(vp + j * 8);
#pragma unroll
    for (int j = 0; j < 4; ++j)
#pragma unroll
      for (int e = 0; e < 8; ++e) {
        int row = w * 32 + j * 8 + e;
        Vt[0][row * 64 + (((l >> 3) ^ (row & 7)) << 3) + (l & 7)] = (u16)vv[j][e];
      }
  }
  __syncthreads();

  int cur = 0;
  for (int kvt = 0; kvt <= qtB; ++kvt) {
    const int kv0 = kvt * 64;
    const bool haveNext = (kvt < qtB);
    if (haveNext) {
      const int kvn = kv0 + 64;
#pragma unroll
      for (int i = 0; i < 4; ++i) {
        int r = w * 16 + i * 4 + lg;
        int c = lr ^ (r & 7);
        gload_lds16(Kh + (size_t)(kvn + r) * HD_ + c * 8,
                    (char*)&Ks[cur ^ 1][0] + (w * 16 + i * 4) * 256);
      }
      const u16* vp = Vh + (size_t)(kvn + l) * HD_ + w * 32;
#pragma unroll
      for (int j = 0; j < 4; ++j) vv[j] = *(const short8*)(vp + j * 8);
    }

    f32x4 bias4[4];
#pragma unroll
    for (int nf = 0; nf < 4; ++nf)
      bias4[nf] = *(const f32x4*)(bkv + kv0 + nf * 16 + lg * 4);

    if (kvt <= qtA)
      compute_tile<1>(&Ks[cur][0], &Vt[cur][0], aqB, aqA, oB, oA, mB, dB, mA, dA,
                      bias4, kvt == qtB, kvt == qtA, q0B + lr, q0A + lr, kv0, lr, lg);
    else
      compute_tile<0>(&Ks[cur][0], &Vt[cur][0], aqB, aqA, oB, oA, mB, dB, mA, dA,
                      bias4, kvt == qtB, false, q0B + lr, q0A + lr, kv0, lr, lg);

    if (haveNext) {
#pragma unroll
      for (int j = 0; j < 4; ++j)
#pragma unroll
        for (int e = 0; e < 8; ++e) {
          int row = w * 32 + j * 8 + e;
          Vt[cur ^ 1][row * 64 + (((l >> 3) ^ (row & 7)) << 3) + (l & 7)] = (u16)vv[j][e];
        }
    }
    __syncthreads();
    cur ^= 1;
  }

  // ---- epilogue
  float dvB[4], dvA[4];
#pragma unroll
  for (int r = 0; r < 4; ++r) {
    dvB[r] = __shfl(dB, lg * 4 + r);
    dvA[r] = __shfl(dA, lg * 4 + r);
  }
#pragma unroll
  for (int r = 0; r < 4; ++r) {
    float inv = 1.f / dvB[r];
    size_t row = (size_t)(b * NQ_ + q0B + lg * 4 + r);
#pragma unroll
    for (int nf = 0; nf < 8; ++nf)
      AO[row * D_ + h * HD_ + nf * 16 + lr] = f2bf(oB[nf][r] * inv);
  }
#pragma unroll
  for (int r = 0; r < 4; ++r) {
    float inv = 1.f / dvA[r];
    size_t row = (size_t)(b * NQ_ + q0A + lg * 4 + r);
#pragma unroll
    for (int nf = 0; nf < 8; ++nf)
      AO[row * D_ + h * HD_ + nf * 16 + lr] = f2bf(oA[nf][r] * inv);
  }
}

// ---------------------------------------------------------------- launch
extern "C" void kernel_launch(void* const* d_in, const int* in_sizes, int n_in,
                              void* d_out, int out_size, void* d_ws, size_t ws_size,
                              hipStream_t stream) {
  const float* x     = (const float*)d_in[0];
  const float* k     = (const float*)d_in[1];
  const float* v     = (const float*)d_in[2];
  const int*   labels = (const int*)d_in[3];
  const unsigned char* mask = (const unsigned char*)d_in[4];
  const float* q_w   = (const float*)d_in[5];
  const float* q_b   = (const float*)d_in[6];
  const float* out_w = (const float*)d_in[7];
  const float* out_b = (const float*)d_in[8];
  const float* tbias = (const float*)d_in[9];

  char* ws = (char*)d_ws;
  u16* x_bf  = (u16*)(ws + 0);          // 16.8MB
  u16* qw_bf = (u16*)(ws + 16777216);   // 8.4MB
  u16* ow_bf = (u16*)(ws + 25165824);   // 8.4MB
  u16* k_bf  = (u16*)(ws + 33554432);   // 16.8MB
  u16* v_bf  = (u16*)(ws + 50331648);   // 16.8MB
  u16* q_bf  = (u16*)(ws + 67108864);   // 16.8MB
  u16* ao_bf = (u16*)(ws + 83886080);   // 16.8MB
  float* bkv = (float*)(ws + 100663296);// 16KB

  cast_all<<<16384, 256, 0, stream>>>(x, q_w, out_w, k, v,
                                      x_bf, qw_bf, ow_bf, k_bf, v_bf);
  build_bias<<<16, 256, 0, stream>>>(labels, mask, tbias, bkv, B_ * NKV_);

  gemm_bt<1><<<512, 256, 0, stream>>>(x_bf, qw_bf, q_b, (void*)q_bf, MM_, D_, D_, QSCALE);
  attn_fwd<<<512, 256, 0, stream>>>(q_bf, k_bf, v_bf, bkv, ao_bf);
  gemm_bt<0><<<512, 256, 0, stream>>>(ao_bf, ow_bf, out_b, d_out, MM_, D_, D_, 1.0f);
}

// Round 4
// 389.056 us; speedup vs baseline: 1.0384x; 1.0062x over previous
//
#include <hip/hip_runtime.h>
#include <stdint.h>

typedef unsigned short u16;
typedef __attribute__((ext_vector_type(8))) short short8;
typedef __attribute__((ext_vector_type(4))) float f32x4;
typedef __attribute__((ext_vector_type(4))) uint32_t u32x4;

#define B_   2
#define NQ_  2048
#define NKV_ 2048
#define D_   2048
#define H_   16
#define HD_  128
#define MM_  (B_*NQ_)   // 4096
#define LOG2E 1.4426950408889634f
#define QSCALE (0.08838834764831845f * 1.4426950408889634f)

__device__ __forceinline__ u16 f2bf(float f) {
  uint32_t u = __float_as_uint(f);
  u += 0x7fffu + ((u >> 16) & 1u);
  return (u16)(u >> 16);
}

__device__ __forceinline__ uint32_t cvtpk(float lo, float hi) {
  uint32_t r;
  asm("v_cvt_pk_bf16_f32 %0, %1, %2" : "=v"(r) : "v"(lo), "v"(hi));
  return r;
}

__device__ __forceinline__ void gload_lds16(const void* g, void* l) {
  __builtin_amdgcn_global_load_lds(
      (const __attribute__((address_space(1))) void*)g,
      (__attribute__((address_space(3))) void*)l, 16, 0, 0);
}

// ---------------------------------------------------------------- fused casts
__global__ __launch_bounds__(256) void cast_all(
    const float* __restrict__ x,  const float* __restrict__ qw,
    const float* __restrict__ ow, const float* __restrict__ k,
    const float* __restrict__ v,
    u16* __restrict__ xo, u16* __restrict__ qwo, u16* __restrict__ owo,
    u16* __restrict__ ko, u16* __restrict__ vo)
{
  int i = blockIdx.x * 256 + threadIdx.x;   // units of 8 floats
  const float* s; u16* d; int off;
  if      (i < 1048576) { s = x;  d = xo;  off = i; }
  else if (i < 1572864) { s = qw; d = qwo; off = i - 1048576; }
  else if (i < 2097152) { s = ow; d = owo; off = i - 1572864; }
  else if (i < 3145728) { s = k;  d = ko;  off = i - 2097152; }
  else                  { s = v;  d = vo;  off = i - 3145728; }
  const float4* sp = (const float4*)s + (size_t)off * 2;
  float4 a = sp[0], b = sp[1];
  short8 o;
  o[0] = (short)f2bf(a.x); o[1] = (short)f2bf(a.y);
  o[2] = (short)f2bf(a.z); o[3] = (short)f2bf(a.w);
  o[4] = (short)f2bf(b.x); o[5] = (short)f2bf(b.y);
  o[6] = (short)f2bf(b.z); o[7] = (short)f2bf(b.w);
  *((short8*)d + off) = o;
}

__global__ __launch_bounds__(256) void build_bias(const int* __restrict__ labels,
                                                  const unsigned char* __restrict__ mask,
                                                  const float* __restrict__ tb,
                                                  float* __restrict__ out, int n) {
  int i = blockIdx.x * 256 + threadIdx.x;
  if (i < n) out[i] = mask[i] ? -1e30f : tb[labels[i]] * LOG2E;
}

// ---------------------------------------------------------------- GEMM (pipelined)
// C[M=4096][N=2048] = (A @ W^T + bias) * escale, A[4096][2048], W[2048][2048] bf16.
// 256x128 tile, BK=64, 512 thr (8 waves: 2M x 4N), wave out 128x32.
// LDS: 6 half-slots per operand (A-half 128x64=16KB, B-half 64x64=8KB) = 144KB
//  -> 3 K-tiles resident. Stage tile t+2 during iter t (slot of t-1, freed).
// Per phase: vmcnt(N) + raw s_barrier + 12 ds_read_b128 + stage + 16 MFMA.
// vmcnt ledger (6 loads/iter: p0 = Alo(2)+Blo(1), p1 = Ahi(2)+Bhi(1)):
//  dep of iter t = Bhi(t) issued @ iter t-2 p1 -> vmcnt(6) @p0, vmcnt(9) @p1.
template<int OUT_BF16>
__global__ __launch_bounds__(512, 2) void gemm8(
    const u16* __restrict__ A, const u16* __restrict__ W,
    const float* __restrict__ bias, void* __restrict__ Cout, float escale)
{
  __shared__ u16 Ah[6][128 * 64];   // 96KB
  __shared__ u16 Bh[6][64 * 64];    // 48KB
  const int tid = threadIdx.x;
  const int w = tid >> 6, l = tid & 63;
  const int lr = l & 15, lg = l >> 4;
  const int wm = w >> 2, wn = w & 3;
  int bid = blockIdx.x;
  int swz = (bid & 7) * 32 + (bid >> 3);   // 256 blocks, bijective
  const int bm = swz >> 4, bn = swz & 15;

  f32x4 acc[8][2] = {};

  const int srl = l >> 3;   // lane sub-row
  const int scl = l & 7;    // lane chunk

  auto stageA = [&](int t, int h) {
#pragma unroll
    for (int j = 0; j < 2; ++j) {
      int r = w * 16 + j * 8 + srl;
      int gc = t * 64 + ((scl ^ (r & 7)) << 3);
      gload_lds16(A + (size_t)(bm * 256 + h * 128 + r) * 2048 + gc,
                  &Ah[(2 * t + h) % 6][(w * 16 + j * 8) * 64]);
    }
  };
  auto stageB = [&](int t, int h) {
    int r = w * 8 + srl;
    int gc = t * 64 + ((scl ^ (r & 7)) << 3);
    gload_lds16(W + (size_t)(bn * 128 + h * 64 + r) * 2048 + gc,
                &Bh[(2 * t + h) % 6][(w * 8) * 64]);
  };

#define GPHASE(MH, VMSTR, DOSTAGE, t) do {                                     \
    asm volatile(VMSTR ::: "memory");                                          \
    __builtin_amdgcn_s_barrier();                                              \
    __builtin_amdgcn_sched_barrier(0);                                         \
    const u16* pa = &Ah[(2 * (t) + wm) % 6][0];                                \
    const u16* pb = &Bh[(2 * (t) + (wn >> 1)) % 6][0];                         \
    short8 av[4][2], bv[2][2];                                                 \
    _Pragma("unroll") for (int mf = 0; mf < 4; ++mf) {                         \
      int row = MH * 64 + mf * 16 + lr;                                        \
      _Pragma("unroll") for (int ks = 0; ks < 2; ++ks) {                       \
        int ch = (ks * 4 + lg) ^ (row & 7);                                    \
        av[mf][ks] = *(const short8*)((const char*)pa + row * 128 + ch * 16);  \
      } }                                                                      \
    _Pragma("unroll") for (int nf = 0; nf < 2; ++nf) {                         \
      int row = (wn & 1) * 32 + nf * 16 + lr;                                  \
      _Pragma("unroll") for (int ks = 0; ks < 2; ++ks) {                       \
        int ch = (ks * 4 + lg) ^ (row & 7);                                    \
        bv[nf][ks] = *(const short8*)((const char*)pb + row * 128 + ch * 16);  \
      } }                                                                      \
    if (DOSTAGE) { stageA((t) + 2, MH); stageB((t) + 2, MH); }                 \
    __builtin_amdgcn_s_setprio(1);                                             \
    _Pragma("unroll") for (int mf = 0; mf < 4; ++mf)                           \
      _Pragma("unroll") for (int nf = 0; nf < 2; ++nf)                         \
        _Pragma("unroll") for (int ks = 0; ks < 2; ++ks)                       \
          acc[MH * 4 + mf][nf] = __builtin_amdgcn_mfma_f32_16x16x32_bf16(      \
              av[mf][ks], bv[nf][ks], acc[MH * 4 + mf][nf], 0, 0, 0);          \
    __builtin_amdgcn_s_setprio(0);                                             \
  } while (0)

  // prologue: tiles 0,1 in steady-state issue order
  stageA(0, 0); stageB(0, 0); stageA(0, 1); stageB(0, 1);
  stageA(1, 0); stageB(1, 0); stageA(1, 1); stageB(1, 1);

  for (int t = 0; t < 30; ++t) {          // NT-2 = 30
    GPHASE(0, "s_waitcnt vmcnt(6)", 1, t);
    GPHASE(1, "s_waitcnt vmcnt(9)", 1, t);
  }
  GPHASE(0, "s_waitcnt vmcnt(6)", 0, 30);
  GPHASE(1, "s_waitcnt vmcnt(6)", 0, 30);
  GPHASE(0, "s_waitcnt vmcnt(0)", 0, 31);
  GPHASE(1, "s_waitcnt vmcnt(0)", 0, 31);
#undef GPHASE

  // epilogue
#pragma unroll
  for (int nf = 0; nf < 2; ++nf) {
    int col = bn * 128 + wn * 32 + nf * 16 + lr;
    float bb = bias[col];
#pragma unroll
    for (int mfg = 0; mfg < 8; ++mfg) {
#pragma unroll
      for (int r = 0; r < 4; ++r) {
        size_t row = (size_t)(bm * 256 + wm * 128 + mfg * 16 + lg * 4 + r);
        float vv = (acc[mfg][nf][r] + bb) * escale;
        if (OUT_BF16) ((u16*)Cout)[row * 2048 + col] = f2bf(vv);
        else          ((float*)Cout)[row * 2048 + col] = vv;
      }
    }
  }
}

// ---------------------------------------------------------------- attention (unchanged from R3)
__device__ __forceinline__ void softmax16(
    const f32x4 s[4], const f32x4 bias4[4], bool diag, int qrow, int kv0,
    int lr, int lg, float& m, float& d, f32x4 o[8], short8 ap[2])
{
  float sv[4][4];
  float pm = -3e38f;
#pragma unroll
  for (int nf = 0; nf < 4; ++nf)
#pragma unroll
    for (int r = 0; r < 4; ++r) {
      float v = s[nf][r] + bias4[nf][r];
      if (diag) {
        int kv = kv0 + nf * 16 + lg * 4 + r;
        if (kv > qrow) v = -1e30f;
      }
      sv[nf][r] = v;
      pm = fmaxf(pm, v);
    }
  pm = fmaxf(pm, __shfl_xor(pm, 16));
  pm = fmaxf(pm, __shfl_xor(pm, 32));
  if (__any(pm > m + 8.f)) {
    float mn = fmaxf(m, pm);
    float al = __builtin_exp2f(m - mn);
    m = mn;
    d *= al;
    float alr[4];
#pragma unroll
    for (int r = 0; r < 4; ++r) alr[r] = __shfl(al, lg * 4 + r);
#pragma unroll
    for (int nf = 0; nf < 8; ++nf) {
      o[nf][0] *= alr[0]; o[nf][1] *= alr[1];
      o[nf][2] *= alr[2]; o[nf][3] *= alr[3];
    }
  }
  float ps = 0.f;
  uint32_t pk0[4], pk1[4];
#pragma unroll
  for (int nf = 0; nf < 4; ++nf) {
    float p0 = __builtin_exp2f(sv[nf][0] - m);
    float p1 = __builtin_exp2f(sv[nf][1] - m);
    float p2 = __builtin_exp2f(sv[nf][2] - m);
    float p3 = __builtin_exp2f(sv[nf][3] - m);
    ps += (p0 + p1) + (p2 + p3);
    pk0[nf] = cvtpk(p0, p1);
    pk1[nf] = cvtpk(p2, p3);
  }
  ps += __shfl_xor(ps, 16);
  ps += __shfl_xor(ps, 32);
  d += ps;
#pragma unroll
  for (int ks = 0; ks < 2; ++ks) {
    uint32_t rr[4];
#pragma unroll
    for (int i = 0; i < 4; ++i) {
      uint32_t c0 = ((lg & 1) == (i >> 1)) ? pk0[2 * ks] : pk0[2 * ks + 1];
      uint32_t c1 = ((lg & 1) == (i >> 1)) ? pk1[2 * ks] : pk1[2 * ks + 1];
      uint32_t contrib = (i & 1) ? c1 : c0;
      int srclg = (lg & 1) * 2 + ((i >> 1) ^ (lg >> 1));
      rr[i] = (uint32_t)__shfl((int)contrib, lr + 16 * srclg);
    }
    u32x4 t4;
    t4[0] = (lg & 2) ? rr[2] : rr[0];
    t4[1] = (lg & 2) ? rr[3] : rr[1];
    t4[2] = (lg & 2) ? rr[0] : rr[2];
    t4[3] = (lg & 2) ? rr[1] : rr[3];
    ap[ks] = __builtin_bit_cast(short8, t4);
  }
}

template<int WA>
__device__ __forceinline__ void compute_tile(
    const u16* __restrict__ ksb, const u16* __restrict__ vtb,
    const short8 aqB[4], const short8 aqA[4],
    f32x4 oB[8], f32x4 oA[8],
    float& mB, float& dB, float& mA, float& dA,
    const f32x4 bias4[4], bool diagB, bool diagA,
    int qrowB, int qrowA, int kv0, int lr, int lg)
{
  f32x4 sB[4] = {}, sA[4] = {};
  __builtin_amdgcn_s_setprio(1);
#pragma unroll
  for (int nf = 0; nf < 4; ++nf) {
#pragma unroll
    for (int ks = 0; ks < 4; ++ks) {
      int row = nf * 16 + lr;
      int pch = (ks * 4 + lg) ^ (row & 7);
      short8 bk = *(const short8*)((const char*)ksb + row * 256 + pch * 16);
      sB[nf] = __builtin_amdgcn_mfma_f32_16x16x32_bf16(bk, aqB[ks], sB[nf], 0, 0, 0);
      if (WA) sA[nf] = __builtin_amdgcn_mfma_f32_16x16x32_bf16(bk, aqA[ks], sA[nf], 0, 0, 0);
    }
  }
  __builtin_amdgcn_s_setprio(0);

  short8 apB[2], apA[2];
  softmax16(sB, bias4, diagB, qrowB, kv0, lr, lg, mB, dB, oB, apB);
  if (WA) softmax16(sA, bias4, diagA, qrowA, kv0, lr, lg, mA, dA, oA, apA);

  __builtin_amdgcn_s_setprio(1);
#pragma unroll
  for (int ks = 0; ks < 2; ++ks) {
#pragma unroll
    for (int nf = 0; nf < 8; ++nf) {
      int rowv = nf * 16 + lr;
      short8 bv = *(const short8*)(vtb + rowv * 64 + (((ks * 4 + lg) ^ (lr & 7)) << 3));
      oB[nf] = __builtin_amdgcn_mfma_f32_16x16x32_bf16(apB[ks], bv, oB[nf], 0, 0, 0);
      if (WA) oA[nf] = __builtin_amdgcn_mfma_f32_16x16x32_bf16(apA[ks], bv, oA[nf], 0, 0, 0);
    }
  }
  __builtin_amdgcn_s_setprio(0);
}

__global__ __launch_bounds__(256, 2) void attn_fwd(
    const u16* __restrict__ Q, const u16* __restrict__ Kg,
    const u16* __restrict__ Vg, const float* __restrict__ biaskv,
    u16* __restrict__ AO)
{
  __shared__ u16 Ks[2][64 * 128];
  __shared__ u16 Vt[2][128 * 64];

  const int tid = threadIdx.x;
  const int w = tid >> 6, l = tid & 63;
  const int lr = l & 15, lg = l >> 4;

  const int bid = blockIdx.x;
  const int bh = bid & 31, pi = bid >> 5;
  const int b = bh >> 4, h = bh & 15;
  const int qtA = pi, qtB = 31 - pi;

  const size_t kvbase = ((size_t)bh) * NKV_ * HD_;
  const u16* Kh = Kg + kvbase;
  const u16* Vh = Vg + kvbase;
  const float* bkv = biaskv + b * NKV_;

  const int q0A = qtA * 64 + w * 16;
  const int q0B = qtB * 64 + w * 16;

  short8 aqA[4], aqB[4];
  {
    const u16* qpA = Q + (size_t)(b * NQ_ + q0A + lr) * D_ + h * HD_ + lg * 8;
    const u16* qpB = Q + (size_t)(b * NQ_ + q0B + lr) * D_ + h * HD_ + lg * 8;
#pragma unroll
    for (int ks = 0; ks < 4; ++ks) {
      aqA[ks] = *(const short8*)(qpA + ks * 32);
      aqB[ks] = *(const short8*)(qpB + ks * 32);
    }
  }

  f32x4 oA[8] = {}, oB[8] = {};
  float mA = -1e30f, mB = -1e30f, dA = 0.f, dB = 0.f;

  short8 vv[4];
  {
#pragma unroll
    for (int i = 0; i < 4; ++i) {
      int r = w * 16 + i * 4 + lg;
      int c = lr ^ (r & 7);
      gload_lds16(Kh + (size_t)r * HD_ + c * 8, (char*)&Ks[0][0] + (w * 16 + i * 4) * 256);
    }
    const u16* vp = Vh + (size_t)l * HD_ + w * 32;
#pragma unroll
    for (int j = 0; j < 4; ++j) vv[j] = *(const short8*)(vp + j * 8);
#pragma unroll
    for (int j = 0; j < 4; ++j)
#pragma unroll
      for (int e = 0; e < 8; ++e) {
        int row = w * 32 + j * 8 + e;
        Vt[0][row * 64 + (((l >> 3) ^ (row & 7)) << 3) + (l & 7)] = (u16)vv[j][e];
      }
  }
  __syncthreads();

  int cur = 0;
  for (int kvt = 0; kvt <= qtB; ++kvt) {
    const int kv0 = kvt * 64;
    const bool haveNext = (kvt < qtB);
    if (haveNext) {
      const int kvn = kv0 + 64;
#pragma unroll
      for (int i = 0; i < 4; ++i) {
        int r = w * 16 + i * 4 + lg;
        int c = lr ^ (r & 7);
        gload_lds16(Kh + (size_t)(kvn + r) * HD_ + c * 8,
                    (char*)&Ks[cur ^ 1][0] + (w * 16 + i * 4) * 256);
      }
      const u16* vp = Vh + (size_t)(kvn + l) * HD_ + w * 32;
#pragma unroll
      for (int j = 0; j < 4; ++j) vv[j] = *(const short8*)(vp + j * 8);
    }

    f32x4 bias4[4];
#pragma unroll
    for (int nf = 0; nf < 4; ++nf)
      bias4[nf] = *(const f32x4*)(bkv + kv0 + nf * 16 + lg * 4);

    if (kvt <= qtA)
      compute_tile<1>(&Ks[cur][0], &Vt[cur][0], aqB, aqA, oB, oA, mB, dB, mA, dA,
                      bias4, kvt == qtB, kvt == qtA, q0B + lr, q0A + lr, kv0, lr, lg);
    else
      compute_tile<0>(&Ks[cur][0], &Vt[cur][0], aqB, aqA, oB, oA, mB, dB, mA, dA,
                      bias4, kvt == qtB, false, q0B + lr, q0A + lr, kv0, lr, lg);

    if (haveNext) {
#pragma unroll
      for (int j = 0; j < 4; ++j)
#pragma unroll
        for (int e = 0; e < 8; ++e) {
          int row = w * 32 + j * 8 + e;
          Vt[cur ^ 1][row * 64 + (((l >> 3) ^ (row & 7)) << 3) + (l & 7)] = (u16)vv[j][e];
        }
    }
    __syncthreads();
    cur ^= 1;
  }

  float dvB[4], dvA[4];
#pragma unroll
  for (int r = 0; r < 4; ++r) {
    dvB[r] = __shfl(dB, lg * 4 + r);
    dvA[r] = __shfl(dA, lg * 4 + r);
  }
#pragma unroll
  for (int r = 0; r < 4; ++r) {
    float inv = 1.f / dvB[r];
    size_t row = (size_t)(b * NQ_ + q0B + lg * 4 + r);
#pragma unroll
    for (int nf = 0; nf < 8; ++nf)
      AO[row * D_ + h * HD_ + nf * 16 + lr] = f2bf(oB[nf][r] * inv);
  }
#pragma unroll
  for (int r = 0; r < 4; ++r) {
    float inv = 1.f / dvA[r];
    size_t row = (size_t)(b * NQ_ + q0A + lg * 4 + r);
#pragma unroll
    for (int nf = 0; nf < 8; ++nf)
      AO[row * D_ + h * HD_ + nf * 16 + lr] = f2bf(oA[nf][r] * inv);
  }
}

// ---------------------------------------------------------------- launch
extern "C" void kernel_launch(void* const* d_in, const int* in_sizes, int n_in,
                              void* d_out, int out_size, void* d_ws, size_t ws_size,
                              hipStream_t stream) {
  const float* x     = (const float*)d_in[0];
  const float* k     = (const float*)d_in[1];
  const float* v     = (const float*)d_in[2];
  const int*   labels = (const int*)d_in[3];
  const unsigned char* mask = (const unsigned char*)d_in[4];
  const float* q_w   = (const float*)d_in[5];
  const float* q_b   = (const float*)d_in[6];
  const float* out_w = (const float*)d_in[7];
  const float* out_b = (const float*)d_in[8];
  const float* tbias = (const float*)d_in[9];

  char* ws = (char*)d_ws;
  u16* x_bf  = (u16*)(ws + 0);
  u16* qw_bf = (u16*)(ws + 16777216);
  u16* ow_bf = (u16*)(ws + 25165824);
  u16* k_bf  = (u16*)(ws + 33554432);
  u16* v_bf  = (u16*)(ws + 50331648);
  u16* q_bf  = (u16*)(ws + 67108864);
  u16* ao_bf = (u16*)(ws + 83886080);
  float* bkv = (float*)(ws + 100663296);

  cast_all<<<16384, 256, 0, stream>>>(x, q_w, out_w, k, v,
                                      x_bf, qw_bf, ow_bf, k_bf, v_bf);
  build_bias<<<16, 256, 0, stream>>>(labels, mask, tbias, bkv, B_ * NKV_);

  gemm8<1><<<256, 512, 0, stream>>>(x_bf, qw_bf, q_b, (void*)q_bf, QSCALE);
  attn_fwd<<<512, 256, 0, stream>>>(q_bf, k_bf, v_bf, bkv, ao_bf);
  gemm8<0><<<256, 512, 0, stream>>>(ao_bf, ow_bf, out_b, d_out, 1.0f);
}